// Round 3
// baseline (55.544 us; speedup 1.0000x reference)
//
#include <hip/hip_runtime.h>
#include <cstddef>

#define SLEN 8192
#define CIN  32
#define COUT 8
#define BATCH 128
#define BCHUNK 4

typedef float v2f __attribute__((ext_vector_type(2)));
typedef float v4f __attribute__((ext_vector_type(4)));

// tanh(x) = 1 - 2/(exp(2x)+1). exp overflow -> inf -> rcp(inf)=0 -> +1; underflow -> 0 -> -1.
__device__ __forceinline__ float fast_tanh(float x) {
    float t = __expf(2.0f * x);
    return 1.0f - 2.0f * __builtin_amdgcn_rcpf(t + 1.0f);
}

// Kernel 1: wsum[j,s] = sum_i w1[i,j,s].
// Block = (64 lanes) x (4 i-groups). Each wave sums 8 i's for 64 consecutive
// float4 outputs (coalesced 1KB loads), then LDS-combine across the 4 waves.
__global__ __launch_bounds__(256) void lc3_wsum(const float* __restrict__ w1,
                                                float* __restrict__ wsum) {
    __shared__ v4f part[4][64];
    const int tx = threadIdx.x & 63;
    const int ty = threadIdx.x >> 6;
    const int g  = blockIdx.x * 64 + tx;       // float4-output index, 0..65535
    const int j  = g >> 11;                    // / (SLEN/4)
    const int s4 = g & 2047;

    v4f acc = (v4f)(0.f);
    #pragma unroll
    for (int ii = 0; ii < 8; ++ii) {
        const int i = ty * 8 + ii;
        acc += *reinterpret_cast<const v4f*>(
            &w1[(size_t)(i * CIN + j) * SLEN + (size_t)s4 * 4]);
    }
    part[ty][tx] = acc;
    __syncthreads();
    if (ty == 0) {
        v4f r = part[0][tx] + part[1][tx] + part[2][tx] + part[3][tx];
        *reinterpret_cast<v4f*>(&wsum[(size_t)j * SLEN + (size_t)s4 * 4]) = r;
    }
}

// Kernel 2: per thread: 2 consecutive s positions (v2f), BCHUNK batches, 8 outs.
__global__ __launch_bounds__(256) void lc3_main(const float* __restrict__ x,
                                                const float* __restrict__ w2,
                                                const float* __restrict__ bias,
                                                const float* __restrict__ wsum,
                                                float* __restrict__ out) {
    const int s  = (blockIdx.x * 256 + threadIdx.x) * 2;
    const int b0 = blockIdx.y * BCHUNK;

    v2f acc[BCHUNK][COUT];
    #pragma unroll
    for (int k = 0; k < BCHUNK; ++k)
        #pragma unroll
        for (int o = 0; o < COUT; ++o) acc[k][o] = (v2f)(0.f);

    for (int j = 0; j < CIN; ++j) {
        const v2f wsv = *reinterpret_cast<const v2f*>(&wsum[j * SLEN + s]);
        v2f h[BCHUNK];
        #pragma unroll
        for (int k = 0; k < BCHUNK; ++k) {
            const v2f xv = __builtin_nontemporal_load(
                reinterpret_cast<const v2f*>(&x[((b0 + k) * CIN + j) * SLEN + s]));
            h[k].x = fast_tanh(xv.x * wsv.x);
            h[k].y = fast_tanh(xv.y * wsv.y);
        }
        #pragma unroll
        for (int o = 0; o < COUT; ++o) {
            const v2f wv = *reinterpret_cast<const v2f*>(&w2[(o * CIN + j) * SLEN + s]);
            #pragma unroll
            for (int k = 0; k < BCHUNK; ++k) {
                acc[k][o].x = fmaf(h[k].x, wv.x, acc[k][o].x);
                acc[k][o].y = fmaf(h[k].y, wv.y, acc[k][o].y);
            }
        }
    }

    #pragma unroll
    for (int o = 0; o < COUT; ++o) {
        const v2f bv = *reinterpret_cast<const v2f*>(&bias[o * SLEN + s]);
        #pragma unroll
        for (int k = 0; k < BCHUNK; ++k) {
            v2f r;
            r.x = fast_tanh(acc[k][o].x + bv.x);
            r.y = fast_tanh(acc[k][o].y + bv.y);
            __builtin_nontemporal_store(
                r, reinterpret_cast<v2f*>(&out[((b0 + k) * COUT + o) * SLEN + s]));
        }
    }
}

extern "C" void kernel_launch(void* const* d_in, const int* in_sizes, int n_in,
                              void* d_out, int out_size, void* d_ws, size_t ws_size,
                              hipStream_t stream) {
    const float* x    = (const float*)d_in[0];
    const float* w1   = (const float*)d_in[1];
    const float* w2   = (const float*)d_in[2];
    const float* bias = (const float*)d_in[3];
    float* out  = (float*)d_out;
    float* wsum = (float*)d_ws;   // needs CIN*SLEN*4 = 1 MB; ws is preallocated scratch

    // wsum: 65536 float4 outputs, 64 per block -> 1024 blocks
    lc3_wsum<<<dim3(CIN * SLEN / 4 / 64), dim3(256), 0, stream>>>(w1, wsum);

    // main: 16 x 32 = 512 blocks; stride-16 same-s siblings land on the same XCD
    dim3 grid(SLEN / 2 / 256, BATCH / BCHUNK);
    lc3_main<<<grid, dim3(256), 0, stream>>>(x, w2, bias, wsum, out);
}

// Round 4
// 47.081 us; speedup vs baseline: 1.1797x; 1.1797x over previous
//
#include <hip/hip_runtime.h>
#include <cstddef>

#define SLEN 8192
#define CIN  32
#define COUT 8
#define BATCH 128
#define BCHUNK 4

typedef float v2f __attribute__((ext_vector_type(2)));
typedef float v4f __attribute__((ext_vector_type(4)));

// tanh(x) = 1 - 2/(exp(2x)+1). exp overflow -> inf -> rcp(inf)=0 -> +1; underflow -> 0 -> -1.
__device__ __forceinline__ float fast_tanh(float x) {
    float t = __expf(2.0f * x);
    return 1.0f - 2.0f * __builtin_amdgcn_rcpf(t + 1.0f);
}

// Kernel 1: wsum[j,s] = sum_i w1[i,j,s].
// Block = (64 lanes) x (4 i-groups). Each wave sums 8 i's for 64 consecutive
// float4 outputs (coalesced 1KB loads), then LDS-combine across the 4 waves.
__global__ __launch_bounds__(256) void lc3_wsum(const float* __restrict__ w1,
                                                float* __restrict__ wsum) {
    __shared__ v4f part[4][64];
    const int tx = threadIdx.x & 63;
    const int ty = threadIdx.x >> 6;
    const int g  = blockIdx.x * 64 + tx;       // float4-output index, 0..65535
    const int j  = g >> 11;                    // / (SLEN/4)
    const int s4 = g & 2047;

    v4f acc = (v4f)(0.f);
    #pragma unroll
    for (int ii = 0; ii < 8; ++ii) {
        const int i = ty * 8 + ii;
        acc += *reinterpret_cast<const v4f*>(
            &w1[(size_t)(i * CIN + j) * SLEN + (size_t)s4 * 4]);
    }
    part[ty][tx] = acc;
    __syncthreads();
    if (ty == 0) {
        v4f r = part[0][tx] + part[1][tx] + part[2][tx] + part[3][tx];
        *reinterpret_cast<v4f*>(&wsum[(size_t)j * SLEN + (size_t)s4 * 4]) = r;
    }
}

// Kernel 2: per thread: 2 consecutive s positions (v2f), BCHUNK batches, 8 outs.
// Plain cached loads/stores: the ~200 MB working set is L3-resident across
// graph replays — nontemporal hints forced HBM traffic and cost +12 us (R3).
__global__ __launch_bounds__(256) void lc3_main(const float* __restrict__ x,
                                                const float* __restrict__ w2,
                                                const float* __restrict__ bias,
                                                const float* __restrict__ wsum,
                                                float* __restrict__ out) {
    const int s  = (blockIdx.x * 256 + threadIdx.x) * 2;
    const int b0 = blockIdx.y * BCHUNK;

    v2f acc[BCHUNK][COUT];
    #pragma unroll
    for (int k = 0; k < BCHUNK; ++k)
        #pragma unroll
        for (int o = 0; o < COUT; ++o) acc[k][o] = (v2f)(0.f);

    for (int j = 0; j < CIN; ++j) {
        const v2f wsv = *reinterpret_cast<const v2f*>(&wsum[j * SLEN + s]);
        v2f h[BCHUNK];
        #pragma unroll
        for (int k = 0; k < BCHUNK; ++k) {
            const v2f xv = *reinterpret_cast<const v2f*>(&x[((b0 + k) * CIN + j) * SLEN + s]);
            h[k].x = fast_tanh(xv.x * wsv.x);
            h[k].y = fast_tanh(xv.y * wsv.y);
        }
        #pragma unroll
        for (int o = 0; o < COUT; ++o) {
            const v2f wv = *reinterpret_cast<const v2f*>(&w2[(o * CIN + j) * SLEN + s]);
            #pragma unroll
            for (int k = 0; k < BCHUNK; ++k) {
                acc[k][o].x = fmaf(h[k].x, wv.x, acc[k][o].x);
                acc[k][o].y = fmaf(h[k].y, wv.y, acc[k][o].y);
            }
        }
    }

    #pragma unroll
    for (int o = 0; o < COUT; ++o) {
        const v2f bv = *reinterpret_cast<const v2f*>(&bias[o * SLEN + s]);
        #pragma unroll
        for (int k = 0; k < BCHUNK; ++k) {
            v2f r;
            r.x = fast_tanh(acc[k][o].x + bv.x);
            r.y = fast_tanh(acc[k][o].y + bv.y);
            *reinterpret_cast<v2f*>(&out[((b0 + k) * COUT + o) * SLEN + s]) = r;
        }
    }
}

extern "C" void kernel_launch(void* const* d_in, const int* in_sizes, int n_in,
                              void* d_out, int out_size, void* d_ws, size_t ws_size,
                              hipStream_t stream) {
    const float* x    = (const float*)d_in[0];
    const float* w1   = (const float*)d_in[1];
    const float* w2   = (const float*)d_in[2];
    const float* bias = (const float*)d_in[3];
    float* out  = (float*)d_out;
    float* wsum = (float*)d_ws;   // needs CIN*SLEN*4 = 1 MB; ws is preallocated scratch

    // wsum: 65536 float4 outputs, 64 per block -> 1024 blocks
    lc3_wsum<<<dim3(CIN * SLEN / 4 / 64), dim3(256), 0, stream>>>(w1, wsum);

    // main: 16 x 32 = 512 blocks; stride-16 same-s siblings land on the same XCD
    dim3 grid(SLEN / 2 / 256, BATCH / BCHUNK);
    lc3_main<<<grid, dim3(256), 0, stream>>>(x, w2, bias, wsum, out);
}